// Round 7
// baseline (1003.681 us; speedup 1.0000x reference)
//
#include <hip/hip_runtime.h>
#include <cstdint>

#define B_ 8
#define S_ 128
#define T_ 24
#define E_ 512
#define H_ 512
#define H3_ 1536
#define L_ 256
#define D_ 2048

typedef unsigned long long u64;

__device__ __forceinline__ float fsig(float x) { return 1.0f / (1.0f + __expf(-x)); }
__device__ __forceinline__ float ftanh(float x) { return 1.0f - 2.0f / (1.0f + __expf(2.0f * x)); }
__device__ __forceinline__ float dot4(float4 a, float4 b) {
    return a.x * b.x + a.y * b.y + a.z * b.z + a.w * b.w;
}

// Coherent (LLC-level) accesses: relaxed agent-scope atomics compile to
// global_load/store sc0 sc1 — bypass non-coherent L1/L2, no cache flushes.
__device__ __forceinline__ u64 cohLoadU64(const u64* p) {
    return __hip_atomic_load((u64*)p, __ATOMIC_RELAXED, __HIP_MEMORY_SCOPE_AGENT);
}
__device__ __forceinline__ void cohStoreU64(u64* p, u64 v) {
    __hip_atomic_store(p, v, __ATOMIC_RELAXED, __HIP_MEMORY_SCOPE_AGENT);
}
__device__ __forceinline__ float cohLoadF(const float* p) {
    return __hip_atomic_load((float*)p, __ATOMIC_RELAXED, __HIP_MEMORY_SCOPE_AGENT);
}
__device__ __forceinline__ void cohStoreF(float* p, float v) {
    __hip_atomic_store(p, v, __ATOMIC_RELAXED, __HIP_MEMORY_SCOPE_AGENT);
}
__device__ __forceinline__ int cohLoadInt(const int* p) {
    return __hip_atomic_load((int*)p, __ATOMIC_RELAXED, __HIP_MEMORY_SCOPE_AGENT);
}
__device__ __forceinline__ void cohStoreInt(int* p, int v) {
    __hip_atomic_store(p, v, __ATOMIC_RELAXED, __HIP_MEMORY_SCOPE_AGENT);
}
__device__ __forceinline__ float2 asF2(u64 v) { union { u64 u; float2 f; } x; x.u = v; return x.f; }
__device__ __forceinline__ u64 packF2(float v, float tag) { union { float2 f; u64 u; } x; x.f = make_float2(v, tag); return x.u; }

// ---------------------------------------------------------------------------
// boot: clear tagged exchange buffers + tag lines + index prep (one launch)
// ---------------------------------------------------------------------------
__global__ void k_boot(const int* __restrict__ pre, const int* __restrict__ post,
                       const int* __restrict__ trg,
                       int* __restrict__ idxPre, int* __restrict__ idxPost,
                       int* __restrict__ idxTok, float* __restrict__ wEff,
                       u64* __restrict__ clr, int n, int* __restrict__ tags) {
    int gtid = blockIdx.x * 256 + threadIdx.x;  // 128 x 256 = 32768
    for (int i = gtid; i < n; i += gridDim.x * 256) clr[i] = 0ull;
    if (gtid < 128) tags[gtid] = 0;
    if (gtid < 1024) {
        int s = gtid >> 3, b = gtid & 7;
        idxPre[gtid]  = pre[b * S_ + s];
        idxPost[gtid] = post[b * S_ + s];
    }
    if (gtid < T_ * B_) {
        int t = gtid >> 3, b = gtid & 7;
        idxTok[gtid] = (t == 0) ? pre[b * S_ + (S_ - 1)] : trg[b * T_ + (t - 1)];
    }
    if (gtid < 2048) wEff[gtid] = 0.f;
}

// ---------------------------------------------------------------------------
// Tiled f32 GEMM body (device fn): C[m][n] = sum_k A[m][k]*B[n][k] + bias[n]
// ---------------------------------------------------------------------------
__device__ void gemm_body(
    const float* __restrict__ A, const int* __restrict__ Aidx, int lda,
    const float* __restrict__ Bm, int ldb,
    const float* __restrict__ bias, float* __restrict__ C,
    int N, int K, int gbx, int gby) {
    __shared__ float As[16][68];
    __shared__ float Bs[16][68];
    const int m0 = gbx * 64, n0 = gby * 64;
    const int tid = threadIdx.x;
    const int tm = tid >> 2;
    const int tk = (tid & 3) << 2;
    const int tx = tid & 15, ty = tid >> 4;
    const int am = m0 + tm;
    const float* Arow = A + (size_t)(Aidx ? Aidx[am] : am) * lda;
    const float* Brow = Bm + (size_t)(n0 + tm) * ldb;
    float acc[4][4] = {};
    for (int k0 = 0; k0 < K; k0 += 16) {
        float4 av = *(const float4*)(Arow + k0 + tk);
        float4 bv = *(const float4*)(Brow + k0 + tk);
        __syncthreads();
        As[tk][tm] = av.x; As[tk + 1][tm] = av.y; As[tk + 2][tm] = av.z; As[tk + 3][tm] = av.w;
        Bs[tk][tm] = bv.x; Bs[tk + 1][tm] = bv.y; Bs[tk + 2][tm] = bv.z; Bs[tk + 3][tm] = bv.w;
        __syncthreads();
#pragma unroll
        for (int k = 0; k < 16; ++k) {
            float4 a4 = *(const float4*)(&As[k][ty << 2]);
            float4 b4 = *(const float4*)(&Bs[k][tx << 2]);
            float ar[4] = {a4.x, a4.y, a4.z, a4.w};
            float br[4] = {b4.x, b4.y, b4.z, b4.w};
#pragma unroll
            for (int i = 0; i < 4; ++i)
#pragma unroll
                for (int j = 0; j < 4; ++j) acc[i][j] += ar[i] * br[j];
        }
    }
    float4 bb = bias ? *(const float4*)(bias + n0 + (tx << 2)) : make_float4(0.f, 0.f, 0.f, 0.f);
#pragma unroll
    for (int i = 0; i < 4; ++i) {
        int m = m0 + (ty << 2) + i;
        float4 o;
        o.x = acc[i][0] + bb.x; o.y = acc[i][1] + bb.y;
        o.z = acc[i][2] + bb.z; o.w = acc[i][3] + bb.w;
        *(float4*)(C + (size_t)m * N + n0 + (tx << 2)) = o;
    }
}

// ---------------------------------------------------------------------------
// k_mid: role-split concurrent launch of the post-encoder prep:
//   [0,72)    giE   = emb[tok] @ WihDec[:, :512].T + bihDec   (3 x 24 tiles)
//   [72,328)  encProj = encOut @ W_enc.T + attnB              (32 x 8 tiles)
//   [328,457) wEff = fc_out_W @ fc_hid_W ; bEff
//   [457,473) hBuf = tanh([pre_h, post_h] @ fc_enc_W.T + b)
// ---------------------------------------------------------------------------
__global__ __launch_bounds__(256) void k_mid(
    const float* __restrict__ emb, const int* __restrict__ idxTok,
    const float* __restrict__ WihDec, const float* __restrict__ bihDec, float* __restrict__ giE,
    const float* __restrict__ encOut, const float* __restrict__ attnW,
    const float* __restrict__ attnB, float* __restrict__ encProj,
    const float* __restrict__ fcHidW, const float* __restrict__ fcHidB,
    const float* __restrict__ fcOutW, const float* __restrict__ fcOutB,
    float* __restrict__ wEff, float* __restrict__ bEff,
    const float* __restrict__ fcEncW, const float* __restrict__ fcEncB,
    float* __restrict__ hBuf) {
    const int bx = blockIdx.x;
    const int tid = threadIdx.x;
    if (bx < 72) {
        gemm_body(emb, idxTok, 512, WihDec, 1024, bihDec, giE, 1536, 512, bx % 3, bx / 3);
    } else if (bx < 328) {
        int r = bx - 72;
        gemm_body(encOut, nullptr, 512, attnW + 512, 1024, attnB, encProj, 512, 512, r & 31, r >> 5);
    } else if (bx < 457) {
        __shared__ float red[256];
        int wb = bx - 328;
        if (wb < 128) {
            int cblk = wb & 7, q = wb >> 3;
            int col = cblk * 256 + tid;
            int j0 = q * 128;
            float acc = 0.f;
            for (int j = j0; j < j0 + 128; ++j) acc += fcOutW[j] * fcHidW[(size_t)j * D_ + col];
            atomicAdd(wEff + col, acc);
        } else {
            float p = 0.f;
            for (int j = tid; j < D_; j += 256) p += fcOutW[j] * fcHidB[j];
            red[tid] = p;
            __syncthreads();
            for (int s = 128; s > 0; s >>= 1) {
                if (tid < s) red[tid] += red[tid + s];
                __syncthreads();
            }
            if (tid == 0) bEff[0] = red[0] + fcOutB[0];
        }
    } else {
        int o = (bx - 457) * 256 + tid;  // 4096
        int b = o >> 9, j = o & 511;
        const float4* w4 = (const float4*)(fcEncW + (size_t)j * 1024);
        const float4* pre4 = (const float4*)(encOut + (((size_t)(b << 8) + 127) << 9));
        const float4* post4 = (const float4*)(encOut + (((size_t)(b << 8) + 255) << 9));
        float acc = fcEncB[j];
        for (int k = 0; k < 128; ++k) acc += dot4(w4[k], pre4[k]);
        for (int k = 0; k < 128; ++k) acc += dot4(w4[128 + k], post4[k]);
        hBuf[o] = ftanh(acc);
    }
}

// ---------------------------------------------------------------------------
// Encoder scan, col-split + h-broadcast tagged sync, gi inlined (unchanged
// from round 6: fused detect+data single-trip poll is latency-optimal here).
// ---------------------------------------------------------------------------
__global__ __launch_bounds__(512, 2) void k_encoder(
    const float* __restrict__ emb, const int* __restrict__ idxPre, const int* __restrict__ idxPost,
    const float* __restrict__ WihPre, const float* __restrict__ WihPost,
    const float* __restrict__ bihPre, const float* __restrict__ bihPost,
    const float* __restrict__ WhhPre, const float* __restrict__ WhhPost,
    const float* __restrict__ bhhPre, const float* __restrict__ bhhPost,
    float* __restrict__ encOut, u64* __restrict__ encEx) {
    const int bx = blockIdx.x;        // 0..255
    const int chain = bx >> 4;        // gr = chain>>3, b = chain&7
    const int p = bx & 15;
    const int gr = chain >> 3, b = chain & 7;
    const int kb = p << 5;
    const int tid = threadIdx.x;
    const int c = tid >> 4, l = tid & 15;
    const int j = kb + c;
    const float* Wih = gr ? WihPost : WihPre;
    const float* bih = gr ? bihPost : bihPre;
    const float* Whh = gr ? WhhPost : WhhPre;
    const float* bhh = gr ? bhhPost : bhhPre;
    const int* idx = gr ? idxPost : idxPre;
    u64* ex0 = encEx + chain * 512;

    __shared__ float hS[576];   // [16 segs][36] padded
    __shared__ float eS[576];

    float wr[32], wz[32], wn[32], ur[32], uz[32], un[32];
    {
        const float* r0 = Whh + (size_t)j * 512 + l * 32;
        const float* r1 = r0 + 512 * 512;
        const float* r2 = r1 + 512 * 512;
        const float* u0 = Wih + (size_t)j * 512 + l * 32;
        const float* u1 = u0 + 512 * 512;
        const float* u2 = u1 + 512 * 512;
#pragma unroll
        for (int m = 0; m < 32; ++m) {
            wr[m] = r0[m]; wz[m] = r1[m]; wn[m] = r2[m];
            ur[m] = u0[m]; uz[m] = u1[m]; un[m] = u2[m];
        }
    }
    const float b0 = bih[j] + bhh[j];
    const float b1 = bih[512 + j] + bhh[512 + j];
    const float bi2 = bih[1024 + j];
    const float bh2 = bhh[1024 + j];

    for (int t = 0; t < S_; ++t) {
        int tok = idx[t * 8 + b];
        float ev = emb[(size_t)tok * 512 + tid];   // issued early, hides under poll
        if (t == 0) {
            hS[(tid >> 5) * 36 + (tid & 31)] = 0.f;
        } else {
            const float tag = (float)t;
            const u64* src = ex0 + (t & 1) * 8192;
            float v;
            for (;;) {
                float2 f = asF2(cohLoadU64(src + tid));
                if (f.y == tag) { v = f.x; break; }
                __builtin_amdgcn_s_sleep(1);
            }
            hS[(tid >> 5) * 36 + (tid & 31)] = v;
        }
        eS[(tid >> 5) * 36 + (tid & 31)] = ev;
        __syncthreads();
        const float* hseg = hS + l * 36;
        const float* eseg = eS + l * 36;
        float a0 = 0.f, a1 = 0.f, a2h = 0.f, a2i = 0.f;
#pragma unroll
        for (int m = 0; m < 32; ++m) {
            float hv = hseg[m], evv = eseg[m];
            a0 += wr[m] * hv + ur[m] * evv;
            a1 += wz[m] * hv + uz[m] * evv;
            a2h += wn[m] * hv;
            a2i += un[m] * evv;
        }
#pragma unroll
        for (int off = 8; off; off >>= 1) {
            a0 += __shfl_xor(a0, off, 16);
            a1 += __shfl_xor(a1, off, 16);
            a2h += __shfl_xor(a2h, off, 16);
            a2i += __shfl_xor(a2i, off, 16);
        }
        if (l == 0) {
            float r = fsig(a0 + b0);
            float z = fsig(a1 + b1);
            float n = ftanh(a2i + bi2 + r * (a2h + bh2));
            float h2 = (1.f - z) * n + z * hS[p * 36 + c];
            cohStoreU64(ex0 + ((t + 1) & 1) * 8192 + j, packF2(h2, (float)(t + 1)));
            encOut[(((size_t)(b << 8) + (gr << 7) + t) << 9) + j] = h2;
        }
        __syncthreads();
    }
}

// ---------------------------------------------------------------------------
// Decoder: 3-hop dataflow with DETECT/DATA SPLIT (round-7 change):
//  - gruTag[32] monotone ints: WG g sets t+2 after a __syncthreads drain of
//    its h(t+1) store (hEx, plain f32) and hp-partial stores (hpD, plain f32).
//    One tag covers both. Readers poll 1 int/thread (tid<32) + syncthreads_and
//    — ~130 B/iteration instead of re-reading 16-128 KB of tagged atoms
//    (round-6's repoll traffic: FETCH 130 MB, 423 GB/s).
//  - wtTag[64]: same for the weighted vectors (wtEx plain f32).
//  - scEx stays per-slot tagged u64 (256 slots: fused detect+data optimal).
// WAR safety (parity-2 buffers, no clears): a producer's parity-p write at
// step t+2 transitively follows (via gruTag>=t+3 <= all-GRU end-of-step t+1
// <= each GRU finished step t) every parity-p read at step t.
//   roles: [0,32) GRU | [32,96) SC (b,lq) | [96,160) WT (b,cq)
//          [160,164) encdot | [164,188) edot4   (shadow work)
// ---------------------------------------------------------------------------
__global__ __launch_bounds__(512, 2) void k_decoder(
    const float* __restrict__ encOut, const float* __restrict__ encProj,
    const float* __restrict__ attnW, const float* __restrict__ attnV,
    const float* __restrict__ WihDec, const float* __restrict__ WhhDec,
    const float* __restrict__ bhhDec, const float* __restrict__ giE,
    const float* __restrict__ wEff, const float* __restrict__ hBuf,
    const float* __restrict__ emb, const int* __restrict__ idxTok,
    float* __restrict__ hEx, float* __restrict__ hpD,
    u64* __restrict__ scEx, float* __restrict__ wtEx,
    int* __restrict__ gruTag, int* __restrict__ wtTag,
    float* __restrict__ cpart, float* __restrict__ encDot, float* __restrict__ eDot4) {
    const int tid = threadIdx.x;
    const int bx = blockIdx.x;
    __shared__ float shm[9664];

    if (bx < 32) {
        // ================= GRU =================
        const int g = bx;
        const int s = tid >> 5, kq = tid & 31;
        const int j = (g << 4) + s;
        float wr[16], wz[16], wn[16], vr[16], vz[16], vn[16], ap[16];
#pragma unroll
        for (int m = 0; m < 16; ++m) {
            int k = kq + 32 * m;
            wr[m] = WhhDec[(size_t)j * 512 + k];
            wz[m] = WhhDec[(size_t)(512 + j) * 512 + k];
            wn[m] = WhhDec[(size_t)(1024 + j) * 512 + k];
            vr[m] = WihDec[(size_t)j * 1024 + 512 + k];
            vz[m] = WihDec[(size_t)(512 + j) * 1024 + 512 + k];
            vn[m] = WihDec[(size_t)(1024 + j) * 1024 + 512 + k];
            ap[m] = attnW[(size_t)tid * 1024 + (g << 4) + m];  // W_hid row=tid, col=16g+m
        }
        float* hL = shm;          // 4096: full h(t)
        float* xL = shm + 4096;   // 4096: weighted
        float* mS = shm + 8192;   // 1456 scratch
        // mS: [0,384) gh [q48][b8] | [384,768) giw | [768,1152) giE |
        //     [1152,1280) h2 slice [ss][b] | [1280,1328) bhh | [1328,1456) logit
        if (tid < 128) { int ss = tid >> 3, bb = tid & 7; mS[1152 + tid] = hBuf[(bb << 9) + (g << 4) + ss]; }
        if (tid < 48) mS[1280 + tid] = bhhDec[(tid >> 4) * 512 + (g << 4) + (tid & 15)];
        __syncthreads();
        // publish hp partials of h(0) into parity 0; then tag = 1
        {
            float* hdst = hpD + (size_t)g * 4096;
#pragma unroll
            for (int bb = 0; bb < 8; ++bb) {
                float acch = 0.f;
#pragma unroll
                for (int m = 0; m < 16; ++m) acch += ap[m] * mS[1152 + m * 8 + bb];
                cohStoreF(hdst + bb * 512 + tid, acch);
            }
        }
        __syncthreads();
        if (tid == 0) cohStoreInt(gruTag + g, 1);

        for (int t = 0; t < T_; ++t) {
            const int par = t & 1;
            // ---- stage h(t): t==0 from hBuf, else detect(gruTag) + read ----
            if (t == 0) {
#pragma unroll
                for (int i = 0; i < 8; ++i) hL[tid + 512 * i] = hBuf[tid + 512 * i];
                __syncthreads();
            } else {
                const int want = t + 1;
                for (;;) {
                    int tg = want;
                    if (tid < 32) tg = cohLoadInt(gruTag + tid);
                    if (__syncthreads_and(tg >= want)) break;
                    __builtin_amdgcn_s_sleep(2);
                }
                const float* src = hEx + par * 4096;
#pragma unroll
                for (int i = 0; i < 8; ++i) hL[tid + 512 * i] = cohLoadF(src + tid + 512 * i);
                __syncthreads();
            }
            // ---- gh = Whh.h (own 16 cols, all batches) ----
            for (int bb = 0; bb < 8; ++bb) {
                const float* hb = hL + (bb << 9);
                float ar = 0.f, az = 0.f, an = 0.f;
#pragma unroll
                for (int m = 0; m < 16; ++m) {
                    float hv = hb[kq + 32 * m];
                    ar += wr[m] * hv; az += wz[m] * hv; an += wn[m] * hv;
                }
#pragma unroll
                for (int off = 16; off; off >>= 1) {
                    ar += __shfl_xor(ar, off); az += __shfl_xor(az, off); an += __shfl_xor(an, off);
                }
                if (kq == 0) {
                    mS[s * 8 + bb]       = ar;
                    mS[128 + s * 8 + bb] = az;
                    mS[256 + s * 8 + bb] = an;
                }
            }
            // ---- giE prefetch (overlaps wt wait) ----
            if (tid < 384) {
                int bb = tid / 48, idx2 = tid % 48, g3 = idx2 >> 4, ss = idx2 & 15;
                mS[768 + g3 * 128 + ss * 8 + bb] =
                    giE[((size_t)(t << 3) + bb) * H3_ + g3 * 512 + (g << 4) + ss];
            }
            // ---- detect(wtTag) + read weighted ----
            {
                const int want = t + 1;
                for (;;) {
                    int tg = want;
                    if (tid < 64) tg = cohLoadInt(wtTag + tid);
                    if (__syncthreads_and(tg >= want)) break;
                    __builtin_amdgcn_s_sleep(2);
                }
                const float* src = wtEx + par * 4096;
#pragma unroll
                for (int i = 0; i < 8; ++i) xL[tid + 512 * i] = cohLoadF(src + tid + 512 * i);
            }
            __syncthreads();
            // ---- giw = Wih_half . weighted ----
            for (int bb = 0; bb < 8; ++bb) {
                const float* wb = xL + (bb << 9);
                float ar = 0.f, az = 0.f, an = 0.f;
#pragma unroll
                for (int m = 0; m < 16; ++m) {
                    float wv = wb[kq + 32 * m];
                    ar += vr[m] * wv; az += vz[m] * wv; an += vn[m] * wv;
                }
#pragma unroll
                for (int off = 16; off; off >>= 1) {
                    ar += __shfl_xor(ar, off); az += __shfl_xor(az, off); an += __shfl_xor(an, off);
                }
                if (kq == 0) {
                    mS[384 + s * 8 + bb] = ar;
                    mS[512 + s * 8 + bb] = az;
                    mS[640 + s * 8 + bb] = an;
                }
            }
            __syncthreads();
            // ---- gates + h publish (plain f32) + logit partial ----
            if (tid < 128) {
                int ss = tid >> 3, bb = tid & 7;
                int jj = (g << 4) + ss;
                int o = ss * 8 + bb;
                float ghr = mS[o]       + mS[1280 + ss];
                float ghz = mS[128 + o] + mS[1296 + ss];
                float ghn = mS[256 + o] + mS[1312 + ss];
                float gir = mS[384 + o] + mS[768 + o];
                float giz = mS[512 + o] + mS[896 + o];
                float gin = mS[640 + o] + mS[1024 + o];
                float r = fsig(gir + ghr), z = fsig(giz + ghz);
                float n = ftanh(gin + r * ghn);
                float h2 = (1.f - z) * n + z * hL[(bb << 9) + jj];
                cohStoreF(hEx + ((t + 1) & 1) * 4096 + (bb << 9) + jj, h2);
                mS[1152 + o] = h2;
                mS[1328 + o] = h2 * wEff[1024 + jj];
            }
            __syncthreads();
            if (tid < 8) {
                float pc = 0.f;
#pragma unroll
                for (int q = 0; q < 16; ++q) pc += mS[1328 + q * 8 + tid];
                cpart[(tid * T_ + t) * 48 + g] = pc;
            }
            // ---- publish hp partials of h(t+1) into parity (t+1)&1 ----
            if (t < T_ - 1) {
                float* hdst = hpD + (size_t)((t + 1) & 1) * 131072 + (size_t)g * 4096;
#pragma unroll
                for (int bb = 0; bb < 8; ++bb) {
                    float acch = 0.f;
#pragma unroll
                    for (int m = 0; m < 16; ++m) acch += ap[m] * mS[1152 + m * 8 + bb];
                    cohStoreF(hdst + bb * 512 + tid, acch);
                }
                __syncthreads();   // drain hEx + hpD stores of ALL waves
                if (tid == 0) cohStoreInt(gruTag + g, t + 2);
            }
        }
    } else if (bx < 96) {
        // ================= SC =================
        const int id = bx - 32;
        const int b = id >> 3, lq = id & 7;
        float* hpS = shm;          // 512
        float* vS  = shm + 512;    // 512
        vS[tid] = attnV[tid];
        __syncthreads();
        const int kq = tid & 63, lg = tid >> 6;
        for (int t = 0; t < T_; ++t) {
            const int par = t & 1;
            const float tagi = (float)(t + 1);
            // ---- detect(gruTag >= t+1) then one-shot 32-way gather ----
            {
                const int want = t + 1;
                for (;;) {
                    int tg = want;
                    if (tid < 32) tg = cohLoadInt(gruTag + tid);
                    if (__syncthreads_and(tg >= want)) break;
                    __builtin_amdgcn_s_sleep(2);
                }
                const float* src = hpD + (size_t)par * 131072 + (size_t)b * 512 + tid;
                float va[32];
#pragma unroll
                for (int g2 = 0; g2 < 32; ++g2) va[g2] = cohLoadF(src + (size_t)g2 * 4096);
                float sum = 0.f;
#pragma unroll
                for (int g2 = 0; g2 < 32; ++g2) sum += va[g2];
                hpS[tid] = sum;
            }
            __syncthreads();
            u64* dst = scEx + par * 2048 + (b << 8);
#pragma unroll
            for (int i = 0; i < 4; ++i) {
                int ll = lg + (i << 3);
                const float* ep = encProj + (((size_t)(b << 8) + (lq << 5) + ll) << 9);
                float sc = 0.f;
#pragma unroll
                for (int m = 0; m < 8; ++m) {
                    int k = kq + (m << 6);
                    sc += vS[k] * ftanh(ep[k] + hpS[k]);
                }
#pragma unroll
                for (int off = 32; off; off >>= 1) sc += __shfl_xor(sc, off);
                if (kq == 0) cohStoreU64(dst + (lq << 5) + ll, packF2(sc, tagi));
            }
            __syncthreads();
        }
    } else if (bx < 160) {
        // ================= WT =================
        const int id = bx - 96;
        const int b = id >> 3, cq = id & 7;
        const int c = tid & 63, lg = tid >> 6;
        float* aS = shm;          // 256
        float* rS = shm + 256;    // 16
        float* wS = shm + 288;    // 512
        float* lp = shm + 800;    // 64
        for (int t = 0; t < T_; ++t) {
            const int par = t & 1;
            const float tagi = (float)(t + 1);
            float sc = 0.f;
            if (tid < 256) {
                const u64* src = scEx + par * 2048 + (b << 8) + tid;
                for (;;) {
                    float2 f = asF2(cohLoadU64(src));
                    if (f.y == tagi) { sc = f.x; break; }
                    __builtin_amdgcn_s_sleep(1);
                }
            }
            // shfl softmax (waves 0-3 hold the 256 scores)
            float m = (tid < 256) ? sc : -1e30f;
#pragma unroll
            for (int off = 32; off; off >>= 1) m = fmaxf(m, __shfl_xor(m, off));
            if ((tid & 63) == 0) rS[tid >> 6] = m;
            __syncthreads();
            float mx = fmaxf(fmaxf(rS[0], rS[1]), fmaxf(rS[2], rS[3]));
            float e = (tid < 256) ? __expf(sc - mx) : 0.f;
            float ssum = e;
#pragma unroll
            for (int off = 32; off; off >>= 1) ssum += __shfl_xor(ssum, off);
            if ((tid & 63) == 0) rS[8 + (tid >> 6)] = ssum;
            if (tid < 256) aS[tid] = e;
            __syncthreads();
            float inv = 1.f / (rS[8] + rS[9] + rS[10] + rS[11]);
            // weighted cols (complete, no cross-WG reduce); encOut slice L2-hot
            float acc = 0.f;
#pragma unroll
            for (int mm = 0; mm < 32; ++mm) {
                int l = lg + (mm << 3);
                acc += aS[l] * encOut[(((size_t)(b << 8) + l) << 9) + (cq << 6) + c];
            }
            wS[lg * 64 + c] = acc;
            __syncthreads();
            if (tid < 64) {
                float wv = 0.f;
#pragma unroll
                for (int q = 0; q < 8; ++q) wv += wS[q * 64 + tid];
                wv *= inv;
                cohStoreF(wtEx + par * 4096 + (b << 9) + (cq << 6) + tid, wv);
                lp[tid] = wv * wEff[512 + (cq << 6) + tid];
            }
            __syncthreads();   // drain wtEx stores of all waves
            if (tid == 0) {
                cohStoreInt(wtTag + (b << 3) + cq, t + 1);
                float pc = 0.f;
                for (int q = 0; q < 64; ++q) pc += lp[q];
                cpart[(b * T_ + t) * 48 + 32 + cq] = pc;
            }
            __syncthreads();
        }
    } else if (bx < 164) {
        // ================= encdot (shadow) =================
        int wid = tid >> 6, lane = tid & 63;
        int gw = (bx - 160) * 8 + wid;  // 32 waves
        for (int o = gw; o < 2048; o += 32) {
            const float* row = encOut + ((size_t)o << 9);
            float s = 0.f;
            for (int k = lane; k < 512; k += 64) s += row[k] * wEff[k];
            for (int off = 32; off; off >>= 1) s += __shfl_down(s, off);
            if (lane == 0) encDot[o] = s;
        }
    } else {
        // ================= edot4 (shadow) =================
        int wg = bx - 164;              // 24 WGs x 8 rows
        int o = wg * 8 + (tid >> 6);
        int lane = tid & 63;
        const float* row = emb + (size_t)idxTok[o] * E_;
        const float* w = wEff + 1536;
        float s = 0.f;
        for (int k = lane; k < 512; k += 64) s += row[k] * w[k];
        for (int off = 32; off; off >>= 1) s += __shfl_down(s, off);
        if (lane == 0) eDot4[o] = s;
    }
}

// c[b,t] = eDot4 + bEff + sum of 40 partials (32 GRU + 8 WT)
__global__ void k_csum(const float* __restrict__ cpart, const float* __restrict__ eDot4,
                       const float* __restrict__ bEff, float* __restrict__ cBuf) {
    int tid = threadIdx.x;
    if (tid < 192) {
        int b = tid / 24, t = tid % 24;
        float acc = eDot4[t * 8 + b] + bEff[0];
        const float* p = cpart + (b * T_ + t) * 48;
#pragma unroll
        for (int k = 0; k < 40; ++k) acc += p[k];
        cBuf[b * T_ + t] = acc;
    }
}

// out[b,t,l-part] = enc_dot[b,l] + c[b,t]
__global__ void k_final(const float* __restrict__ encDot, const float* __restrict__ c,
                        float* __restrict__ out) {
    int idx = blockIdx.x * 256 + threadIdx.x;  // grid 192 -> 49152
    const int half = B_ * T_ * S_;
    int w = idx < half ? idx : idx - half;
    int b = w / (T_ * S_);
    int r = w % (T_ * S_);
    int t = r / S_, sidx = r % S_;
    int l = (idx < half) ? sidx : (S_ + sidx);
    out[idx] = encDot[b * L_ + l] + c[b * T_ + t];
}

// ---------------------------------------------------------------------------
extern "C" void kernel_launch(void* const* d_in, const int* in_sizes, int n_in,
                              void* d_out, int out_size, void* d_ws, size_t ws_size,
                              hipStream_t stream) {
    const int* pre = (const int*)d_in[0];
    const int* post = (const int*)d_in[1];
    const int* trg = (const int*)d_in[2];
    const float* emb = (const float*)d_in[3];
    const float* WihPre = (const float*)d_in[4];
    const float* WhhPre = (const float*)d_in[5];
    const float* bihPre = (const float*)d_in[6];
    const float* bhhPre = (const float*)d_in[7];
    const float* WihPost = (const float*)d_in[8];
    const float* WhhPost = (const float*)d_in[9];
    const float* bihPost = (const float*)d_in[10];
    const float* bhhPost = (const float*)d_in[11];
    const float* fcEncW = (const float*)d_in[12];
    const float* fcEncB = (const float*)d_in[13];
    const float* attnW = (const float*)d_in[14];
    const float* attnB = (const float*)d_in[15];
    const float* attnV = (const float*)d_in[16];
    const float* WihDec = (const float*)d_in[17];
    const float* WhhDec = (const float*)d_in[18];
    const float* bihDec = (const float*)d_in[19];
    const float* bhhDec = (const float*)d_in[20];
    const float* fcHidW = (const float*)d_in[21];
    const float* fcHidB = (const float*)d_in[22];
    const float* fcOutW = (const float*)d_in[23];
    const float* fcOutB = (const float*)d_in[24];
    float* outp = (float*)d_out;

    float* base = (float*)d_ws;
    size_t off = 0;
    auto alloc = [&](size_t n) {
        float* p = base + off;
        off += (n + 63) & ~(size_t)63;
        return p;
    };
    float* giE = alloc(192 * 1536);
    float* encOut = alloc(8 * 256 * 512);
    float* encProj = alloc(8 * 256 * 512);
    float* wEff = alloc(2048);
    float* bEff = alloc(64);
    float* encDot = alloc(2048);
    float* eDot4 = alloc(256);
    float* hBuf = alloc(4096);
    float* cBuf = alloc(256);
    // tagged region needing clear (contiguous): encEx (u64) + scEx (u64)
    float* encExF = alloc(32768);     // 2 x 16 x 512 u64   encoder h
    float* scExF  = alloc(8192);      // 2 x 2048 u64
    // tag-gated plain-f32 exchange buffers (no clear needed):
    float* hExF  = alloc(8192);       // 2 x 4096 f32       decoder h
    float* hpDF  = alloc(262144);     // 2 x 32 x 8 x 512 f32  hp partials
    float* wtExF = alloc(8192);       // 2 x 4096 f32       weighted
    float* tagsF = alloc(128);        // gruTag[32] + wtTag[64] ints
    float* cpart = alloc(8 * 24 * 48);
    int* idxPre = (int*)alloc(1024);
    int* idxPost = (int*)alloc(1024);
    int* idxTok = (int*)alloc(256);

    int* gruTag = (int*)tagsF;
    int* wtTag = gruTag + 32;

    const int clearN = (32768 + 8192) / 2;  // u64 slots: encEx + scEx
    k_boot<<<128, 256, 0, stream>>>(pre, post, trg, idxPre, idxPost, idxTok, wEff,
                                    (u64*)encExF, clearN, (int*)tagsF);
    k_encoder<<<256, 512, 0, stream>>>(emb, idxPre, idxPost, WihPre, WihPost,
                                       bihPre, bihPost, WhhPre, WhhPost,
                                       bhhPre, bhhPost, encOut, (u64*)encExF);
    k_mid<<<473, 256, 0, stream>>>(emb, idxTok, WihDec, bihDec, giE,
                                   encOut, attnW, attnB, encProj,
                                   fcHidW, fcHidB, fcOutW, fcOutB, wEff, bEff,
                                   fcEncW, fcEncB, hBuf);
    k_decoder<<<188, 512, 0, stream>>>(encOut, encProj, attnW, attnV,
                                       WihDec, WhhDec, bhhDec, giE, wEff, hBuf,
                                       emb, idxTok,
                                       hExF, hpDF, (u64*)scExF, wtExF,
                                       gruTag, wtTag,
                                       cpart, encDot, eDot4);
    k_csum<<<1, 256, 0, stream>>>(cpart, eDot4, bEff, cBuf);
    k_final<<<192, 256, 0, stream>>>(encDot, cBuf, outp);
}

// Round 8
// 921.347 us; speedup vs baseline: 1.0894x; 1.0894x over previous
//
#include <hip/hip_runtime.h>
#include <cstdint>

#define B_ 8
#define S_ 128
#define T_ 24
#define E_ 512
#define H_ 512
#define H3_ 1536
#define L_ 256
#define D_ 2048

typedef unsigned long long u64;

__device__ __forceinline__ float fsig(float x) { return 1.0f / (1.0f + __expf(-x)); }
__device__ __forceinline__ float ftanh(float x) { return 1.0f - 2.0f / (1.0f + __expf(2.0f * x)); }
__device__ __forceinline__ float dot4(float4 a, float4 b) {
    return a.x * b.x + a.y * b.y + a.z * b.z + a.w * b.w;
}

// Coherent (LLC-level) accesses: relaxed agent-scope atomics compile to
// global_load/store sc0 sc1 — bypass non-coherent L1/L2, no cache flushes.
// Cross-kernel visibility of plain stores is fine (L2 flushed at kernel end).
__device__ __forceinline__ u64 cohLoadU64(const u64* p) {
    return __hip_atomic_load((u64*)p, __ATOMIC_RELAXED, __HIP_MEMORY_SCOPE_AGENT);
}
__device__ __forceinline__ void cohStoreU64(u64* p, u64 v) {
    __hip_atomic_store(p, v, __ATOMIC_RELAXED, __HIP_MEMORY_SCOPE_AGENT);
}
__device__ __forceinline__ float cohLoadF(const float* p) {
    return __hip_atomic_load((float*)p, __ATOMIC_RELAXED, __HIP_MEMORY_SCOPE_AGENT);
}
__device__ __forceinline__ void cohAddF(float* p, float v) {
    __hip_atomic_fetch_add(p, v, __ATOMIC_RELAXED, __HIP_MEMORY_SCOPE_AGENT);
}
__device__ __forceinline__ int cohLoadInt(const int* p) {
    return __hip_atomic_load((int*)p, __ATOMIC_RELAXED, __HIP_MEMORY_SCOPE_AGENT);
}
__device__ __forceinline__ void cohAddInt(int* p, int v) {
    __hip_atomic_fetch_add(p, v, __ATOMIC_RELAXED, __HIP_MEMORY_SCOPE_AGENT);
}
__device__ __forceinline__ float2 asF2(u64 v) { union { u64 u; float2 f; } x; x.u = v; return x.f; }
__device__ __forceinline__ u64 packF2(float v, float tag) { union { float2 f; u64 u; } x; x.f = make_float2(v, tag); return x.u; }

// ---------------------------------------------------------------------------
// boot: clear exchange buffers (incl. hpSum/hpCnt) + index prep (one launch).
// Plain stores are safe: L2 is flushed at kernel end, before any consumer.
// ---------------------------------------------------------------------------
__global__ void k_boot(const int* __restrict__ pre, const int* __restrict__ post,
                       const int* __restrict__ trg,
                       int* __restrict__ idxPre, int* __restrict__ idxPost,
                       int* __restrict__ idxTok, float* __restrict__ wEff,
                       u64* __restrict__ clr, int n) {
    int gtid = blockIdx.x * 256 + threadIdx.x;  // 128 x 256 = 32768
    for (int i = gtid; i < n; i += gridDim.x * 256) clr[i] = 0ull;
    if (gtid < 1024) {
        int s = gtid >> 3, b = gtid & 7;
        idxPre[gtid]  = pre[b * S_ + s];
        idxPost[gtid] = post[b * S_ + s];
    }
    if (gtid < T_ * B_) {
        int t = gtid >> 3, b = gtid & 7;
        idxTok[gtid] = (t == 0) ? pre[b * S_ + (S_ - 1)] : trg[b * T_ + (t - 1)];
    }
    if (gtid < 2048) wEff[gtid] = 0.f;
}

// ---------------------------------------------------------------------------
// Tiled f32 GEMM body (device fn): C[m][n] = sum_k A[m][k]*B[n][k] + bias[n]
// ---------------------------------------------------------------------------
__device__ void gemm_body(
    const float* __restrict__ A, const int* __restrict__ Aidx, int lda,
    const float* __restrict__ Bm, int ldb,
    const float* __restrict__ bias, float* __restrict__ C,
    int N, int K, int gbx, int gby) {
    __shared__ float As[16][68];
    __shared__ float Bs[16][68];
    const int m0 = gbx * 64, n0 = gby * 64;
    const int tid = threadIdx.x;
    const int tm = tid >> 2;
    const int tk = (tid & 3) << 2;
    const int tx = tid & 15, ty = tid >> 4;
    const int am = m0 + tm;
    const float* Arow = A + (size_t)(Aidx ? Aidx[am] : am) * lda;
    const float* Brow = Bm + (size_t)(n0 + tm) * ldb;
    float acc[4][4] = {};
    for (int k0 = 0; k0 < K; k0 += 16) {
        float4 av = *(const float4*)(Arow + k0 + tk);
        float4 bv = *(const float4*)(Brow + k0 + tk);
        __syncthreads();
        As[tk][tm] = av.x; As[tk + 1][tm] = av.y; As[tk + 2][tm] = av.z; As[tk + 3][tm] = av.w;
        Bs[tk][tm] = bv.x; Bs[tk + 1][tm] = bv.y; Bs[tk + 2][tm] = bv.z; Bs[tk + 3][tm] = bv.w;
        __syncthreads();
#pragma unroll
        for (int k = 0; k < 16; ++k) {
            float4 a4 = *(const float4*)(&As[k][ty << 2]);
            float4 b4 = *(const float4*)(&Bs[k][tx << 2]);
            float ar[4] = {a4.x, a4.y, a4.z, a4.w};
            float br[4] = {b4.x, b4.y, b4.z, b4.w};
#pragma unroll
            for (int i = 0; i < 4; ++i)
#pragma unroll
                for (int j = 0; j < 4; ++j) acc[i][j] += ar[i] * br[j];
        }
    }
    float4 bb = bias ? *(const float4*)(bias + n0 + (tx << 2)) : make_float4(0.f, 0.f, 0.f, 0.f);
#pragma unroll
    for (int i = 0; i < 4; ++i) {
        int m = m0 + (ty << 2) + i;
        float4 o;
        o.x = acc[i][0] + bb.x; o.y = acc[i][1] + bb.y;
        o.z = acc[i][2] + bb.z; o.w = acc[i][3] + bb.w;
        *(float4*)(C + (size_t)m * N + n0 + (tx << 2)) = o;
    }
}

// ---------------------------------------------------------------------------
// k_mid: role-split concurrent launch of the post-encoder prep:
//   [0,72)    giE   = emb[tok] @ WihDec[:, :512].T + bihDec   (3 x 24 tiles)
//   [72,328)  encProj = encOut @ W_enc.T + attnB              (32 x 8 tiles)
//   [328,457) wEff = fc_out_W @ fc_hid_W ; bEff
//   [457,473) hBuf = tanh([pre_h, post_h] @ fc_enc_W.T + b)
// ---------------------------------------------------------------------------
__global__ __launch_bounds__(256) void k_mid(
    const float* __restrict__ emb, const int* __restrict__ idxTok,
    const float* __restrict__ WihDec, const float* __restrict__ bihDec, float* __restrict__ giE,
    const float* __restrict__ encOut, const float* __restrict__ attnW,
    const float* __restrict__ attnB, float* __restrict__ encProj,
    const float* __restrict__ fcHidW, const float* __restrict__ fcHidB,
    const float* __restrict__ fcOutW, const float* __restrict__ fcOutB,
    float* __restrict__ wEff, float* __restrict__ bEff,
    const float* __restrict__ fcEncW, const float* __restrict__ fcEncB,
    float* __restrict__ hBuf) {
    const int bx = blockIdx.x;
    const int tid = threadIdx.x;
    if (bx < 72) {
        gemm_body(emb, idxTok, 512, WihDec, 1024, bihDec, giE, 1536, 512, bx % 3, bx / 3);
    } else if (bx < 328) {
        int r = bx - 72;
        gemm_body(encOut, nullptr, 512, attnW + 512, 1024, attnB, encProj, 512, 512, r & 31, r >> 5);
    } else if (bx < 457) {
        __shared__ float red[256];
        int wb = bx - 328;
        if (wb < 128) {
            int cblk = wb & 7, q = wb >> 3;
            int col = cblk * 256 + tid;
            int j0 = q * 128;
            float acc = 0.f;
            for (int j = j0; j < j0 + 128; ++j) acc += fcOutW[j] * fcHidW[(size_t)j * D_ + col];
            atomicAdd(wEff + col, acc);
        } else {
            float p = 0.f;
            for (int j = tid; j < D_; j += 256) p += fcOutW[j] * fcHidB[j];
            red[tid] = p;
            __syncthreads();
            for (int s = 128; s > 0; s >>= 1) {
                if (tid < s) red[tid] += red[tid + s];
                __syncthreads();
            }
            if (tid == 0) bEff[0] = red[0] + fcOutB[0];
        }
    } else {
        int o = (bx - 457) * 256 + tid;  // 4096
        int b = o >> 9, j = o & 511;
        const float4* w4 = (const float4*)(fcEncW + (size_t)j * 1024);
        const float4* pre4 = (const float4*)(encOut + (((size_t)(b << 8) + 127) << 9));
        const float4* post4 = (const float4*)(encOut + (((size_t)(b << 8) + 255) << 9));
        float acc = fcEncB[j];
        for (int k = 0; k < 128; ++k) acc += dot4(w4[k], pre4[k]);
        for (int k = 0; k < 128; ++k) acc += dot4(w4[128 + k], post4[k]);
        hBuf[o] = ftanh(acc);
    }
}

// ---------------------------------------------------------------------------
// Encoder scan, col-split + h-broadcast tagged sync, gi inlined (unchanged:
// fused detect+data single-trip poll is latency-optimal here).
// ---------------------------------------------------------------------------
__global__ __launch_bounds__(512, 2) void k_encoder(
    const float* __restrict__ emb, const int* __restrict__ idxPre, const int* __restrict__ idxPost,
    const float* __restrict__ WihPre, const float* __restrict__ WihPost,
    const float* __restrict__ bihPre, const float* __restrict__ bihPost,
    const float* __restrict__ WhhPre, const float* __restrict__ WhhPost,
    const float* __restrict__ bhhPre, const float* __restrict__ bhhPost,
    float* __restrict__ encOut, u64* __restrict__ encEx) {
    const int bx = blockIdx.x;        // 0..255
    const int chain = bx >> 4;        // gr = chain>>3, b = chain&7
    const int p = bx & 15;
    const int gr = chain >> 3, b = chain & 7;
    const int kb = p << 5;
    const int tid = threadIdx.x;
    const int c = tid >> 4, l = tid & 15;
    const int j = kb + c;
    const float* Wih = gr ? WihPost : WihPre;
    const float* bih = gr ? bihPost : bihPre;
    const float* Whh = gr ? WhhPost : WhhPre;
    const float* bhh = gr ? bhhPost : bhhPre;
    const int* idx = gr ? idxPost : idxPre;
    u64* ex0 = encEx + chain * 512;

    __shared__ float hS[576];   // [16 segs][36] padded
    __shared__ float eS[576];

    float wr[32], wz[32], wn[32], ur[32], uz[32], un[32];
    {
        const float* r0 = Whh + (size_t)j * 512 + l * 32;
        const float* r1 = r0 + 512 * 512;
        const float* r2 = r1 + 512 * 512;
        const float* u0 = Wih + (size_t)j * 512 + l * 32;
        const float* u1 = u0 + 512 * 512;
        const float* u2 = u1 + 512 * 512;
#pragma unroll
        for (int m = 0; m < 32; ++m) {
            wr[m] = r0[m]; wz[m] = r1[m]; wn[m] = r2[m];
            ur[m] = u0[m]; uz[m] = u1[m]; un[m] = u2[m];
        }
    }
    const float b0 = bih[j] + bhh[j];
    const float b1 = bih[512 + j] + bhh[512 + j];
    const float bi2 = bih[1024 + j];
    const float bh2 = bhh[1024 + j];

    for (int t = 0; t < S_; ++t) {
        int tok = idx[t * 8 + b];
        float ev = emb[(size_t)tok * 512 + tid];   // issued early, hides under poll
        if (t == 0) {
            hS[(tid >> 5) * 36 + (tid & 31)] = 0.f;
        } else {
            const float tag = (float)t;
            const u64* src = ex0 + (t & 1) * 8192;
            float v;
            for (;;) {
                float2 f = asF2(cohLoadU64(src + tid));
                if (f.y == tag) { v = f.x; break; }
                __builtin_amdgcn_s_sleep(1);
            }
            hS[(tid >> 5) * 36 + (tid & 31)] = v;
        }
        eS[(tid >> 5) * 36 + (tid & 31)] = ev;
        __syncthreads();
        const float* hseg = hS + l * 36;
        const float* eseg = eS + l * 36;
        float a0 = 0.f, a1 = 0.f, a2h = 0.f, a2i = 0.f;
#pragma unroll
        for (int m = 0; m < 32; ++m) {
            float hv = hseg[m], evv = eseg[m];
            a0 += wr[m] * hv + ur[m] * evv;
            a1 += wz[m] * hv + uz[m] * evv;
            a2h += wn[m] * hv;
            a2i += un[m] * evv;
        }
#pragma unroll
        for (int off = 8; off; off >>= 1) {
            a0 += __shfl_xor(a0, off, 16);
            a1 += __shfl_xor(a1, off, 16);
            a2h += __shfl_xor(a2h, off, 16);
            a2i += __shfl_xor(a2i, off, 16);
        }
        if (l == 0) {
            float r = fsig(a0 + b0);
            float z = fsig(a1 + b1);
            float n = ftanh(a2i + bi2 + r * (a2h + bh2));
            float h2 = (1.f - z) * n + z * hS[p * 36 + c];
            cohStoreU64(ex0 + ((t + 1) & 1) * 8192 + j, packF2(h2, (float)(t + 1)));
            encOut[(((size_t)(b << 8) + (gr << 7) + t) << 9) + j] = h2;
        }
        __syncthreads();
    }
}

// ---------------------------------------------------------------------------
// Decoder (round-6 fused-tagged scheme + round-8 hp PUSH-REDUCE):
//  - hp partials: GRU WGs push f32 no-return atomicAdds into hpSum[t]
//    (24 per-step buffers, boot-cleared; no parity/WAR hazard), then
//    __syncthreads (drains vmcnt) + hpCnt[t]++ per WG. SC detects
//    hpCnt[t]==32 (one broadcast line, monotone -> divergent exit safe),
//    then reads its REDUCED 2KB in one RT. Kills round-6's 8.4MB/step
//    64-consumer gather burst (the measured FETCH=130MB pathology).
//  - h / sc / wt stay fused tagged u64 (1-RT; round-7's detect/data split
//    on these cost +1 serial RT each and regressed 107us).
//   roles: [0,32) GRU | [32,96) SC (b,lq) | [96,160) WT (b,cq)
//          [160,164) encdot | [164,188) edot4   (shadow work)
// ---------------------------------------------------------------------------
__global__ __launch_bounds__(512, 2) void k_decoder(
    const float* __restrict__ encOut, const float* __restrict__ encProj,
    const float* __restrict__ attnW, const float* __restrict__ attnV,
    const float* __restrict__ WihDec, const float* __restrict__ WhhDec,
    const float* __restrict__ bhhDec, const float* __restrict__ giE,
    const float* __restrict__ wEff, const float* __restrict__ hBuf,
    const float* __restrict__ emb, const int* __restrict__ idxTok,
    u64* __restrict__ hEx, float* __restrict__ hpSum, int* __restrict__ hpCnt,
    u64* __restrict__ scEx, u64* __restrict__ wtEx,
    float* __restrict__ cpart, float* __restrict__ encDot, float* __restrict__ eDot4) {
    const int tid = threadIdx.x;
    const int bx = blockIdx.x;
    __shared__ float shm[9664];

    if (bx < 32) {
        // ================= GRU =================
        const int g = bx;
        const int s = tid >> 5, kq = tid & 31;
        const int j = (g << 4) + s;
        float wr[16], wz[16], wn[16], vr[16], vz[16], vn[16], ap[16];
#pragma unroll
        for (int m = 0; m < 16; ++m) {
            int k = kq + 32 * m;
            wr[m] = WhhDec[(size_t)j * 512 + k];
            wz[m] = WhhDec[(size_t)(512 + j) * 512 + k];
            wn[m] = WhhDec[(size_t)(1024 + j) * 512 + k];
            vr[m] = WihDec[(size_t)j * 1024 + 512 + k];
            vz[m] = WihDec[(size_t)(512 + j) * 1024 + 512 + k];
            vn[m] = WihDec[(size_t)(1024 + j) * 1024 + 512 + k];
            ap[m] = attnW[(size_t)tid * 1024 + (g << 4) + m];  // W_hid row=tid, col=16g+m
        }
        float* hL = shm;          // 4096: full h(t)
        float* xL = shm + 4096;   // 4096: weighted
        float* mS = shm + 8192;   // 1456 scratch
        // mS: [0,384) gh [q48][b8] | [384,768) giw | [768,1152) giE |
        //     [1152,1280) h2 slice [ss][b] | [1280,1328) bhh | [1328,1456) logit
        if (tid < 128) { int ss = tid >> 3, bb = tid & 7; mS[1152 + tid] = hBuf[(bb << 9) + (g << 4) + ss]; }
        if (tid < 48) mS[1280 + tid] = bhhDec[(tid >> 4) * 512 + (g << 4) + (tid & 15)];
        __syncthreads();
        // push hp partials of h(0) into hpSum[0]; count after drain
        {
#pragma unroll
            for (int bb = 0; bb < 8; ++bb) {
                float acch = 0.f;
#pragma unroll
                for (int m = 0; m < 16; ++m) acch += ap[m] * mS[1152 + m * 8 + bb];
                cohAddF(hpSum + (bb << 9) + tid, acch);
            }
        }
        __syncthreads();  // drains vmcnt: adds at LLC before count
        if (tid == 0) cohAddInt(hpCnt + 0, 1);

        for (int t = 0; t < T_; ++t) {
            const int par = t & 1;
            const float tagi = (float)(t + 1);
            // ---- stage h(t): t==0 from hBuf, else fused tagged poll ----
            if (t == 0) {
#pragma unroll
                for (int i = 0; i < 8; ++i) hL[tid + 512 * i] = hBuf[tid + 512 * i];
            } else {
                const float tagh = (float)t;
                const u64* src = hEx + par * 4096;
                float v[8];
                for (;;) {
                    u64 rr[8]; bool ok = true;
#pragma unroll
                    for (int i = 0; i < 8; ++i) rr[i] = cohLoadU64(src + tid + 512 * i);
#pragma unroll
                    for (int i = 0; i < 8; ++i) { float2 f = asF2(rr[i]); v[i] = f.x; ok &= (f.y == tagh); }
                    if (ok) break;
                    __builtin_amdgcn_s_sleep(1);
                }
#pragma unroll
                for (int i = 0; i < 8; ++i) hL[tid + 512 * i] = v[i];
            }
            __syncthreads();
            // ---- gh = Whh.h (own 16 cols, all batches) ----
            for (int bb = 0; bb < 8; ++bb) {
                const float* hb = hL + (bb << 9);
                float ar = 0.f, az = 0.f, an = 0.f;
#pragma unroll
                for (int m = 0; m < 16; ++m) {
                    float hv = hb[kq + 32 * m];
                    ar += wr[m] * hv; az += wz[m] * hv; an += wn[m] * hv;
                }
#pragma unroll
                for (int off = 16; off; off >>= 1) {
                    ar += __shfl_xor(ar, off); az += __shfl_xor(az, off); an += __shfl_xor(an, off);
                }
                if (kq == 0) {
                    mS[s * 8 + bb]       = ar;
                    mS[128 + s * 8 + bb] = az;
                    mS[256 + s * 8 + bb] = an;
                }
            }
            // ---- giE prefetch (overlaps wt poll) ----
            if (tid < 384) {
                int bb = tid / 48, idx2 = tid % 48, g3 = idx2 >> 4, ss = idx2 & 15;
                mS[768 + g3 * 128 + ss * 8 + bb] =
                    giE[((size_t)(t << 3) + bb) * H3_ + g3 * 512 + (g << 4) + ss];
            }
            // ---- poll weighted (fused tagged, 1 RT) ----
            {
                const u64* src = wtEx + par * 4096;
                float v[8];
                for (;;) {
                    u64 rr[8]; bool ok = true;
#pragma unroll
                    for (int i = 0; i < 8; ++i) rr[i] = cohLoadU64(src + tid + 512 * i);
#pragma unroll
                    for (int i = 0; i < 8; ++i) { float2 f = asF2(rr[i]); v[i] = f.x; ok &= (f.y == tagi); }
                    if (ok) break;
                    __builtin_amdgcn_s_sleep(1);
                }
#pragma unroll
                for (int i = 0; i < 8; ++i) xL[tid + 512 * i] = v[i];
            }
            __syncthreads();
            // ---- giw = Wih_half . weighted ----
            for (int bb = 0; bb < 8; ++bb) {
                const float* wb = xL + (bb << 9);
                float ar = 0.f, az = 0.f, an = 0.f;
#pragma unroll
                for (int m = 0; m < 16; ++m) {
                    float wv = wb[kq + 32 * m];
                    ar += vr[m] * wv; az += vz[m] * wv; an += vn[m] * wv;
                }
#pragma unroll
                for (int off = 16; off; off >>= 1) {
                    ar += __shfl_xor(ar, off); az += __shfl_xor(az, off); an += __shfl_xor(an, off);
                }
                if (kq == 0) {
                    mS[384 + s * 8 + bb] = ar;
                    mS[512 + s * 8 + bb] = az;
                    mS[640 + s * 8 + bb] = an;
                }
            }
            __syncthreads();
            // ---- gates + h publish (fused tagged) + logit partial ----
            if (tid < 128) {
                int ss = tid >> 3, bb = tid & 7;
                int jj = (g << 4) + ss;
                int o = ss * 8 + bb;
                float ghr = mS[o]       + mS[1280 + ss];
                float ghz = mS[128 + o] + mS[1296 + ss];
                float ghn = mS[256 + o] + mS[1312 + ss];
                float gir = mS[384 + o] + mS[768 + o];
                float giz = mS[512 + o] + mS[896 + o];
                float gin = mS[640 + o] + mS[1024 + o];
                float r = fsig(gir + ghr), z = fsig(giz + ghz);
                float n = ftanh(gin + r * ghn);
                float h2 = (1.f - z) * n + z * hL[(bb << 9) + jj];
                cohStoreU64(hEx + ((t + 1) & 1) * 4096 + (bb << 9) + jj, packF2(h2, (float)(t + 1)));
                mS[1152 + o] = h2;
                mS[1328 + o] = h2 * wEff[1024 + jj];
            }
            __syncthreads();
            if (tid < 8) {
                float pc = 0.f;
#pragma unroll
                for (int q = 0; q < 16; ++q) pc += mS[1328 + q * 8 + tid];
                cpart[(tid * T_ + t) * 48 + g] = pc;
            }
            // ---- push hp partials of h(t+1) into hpSum[t+1] ----
            if (t < T_ - 1) {
                float* dst = hpSum + (size_t)(t + 1) * 4096;
#pragma unroll
                for (int bb = 0; bb < 8; ++bb) {
                    float acch = 0.f;
#pragma unroll
                    for (int m = 0; m < 16; ++m) acch += ap[m] * mS[1152 + m * 8 + bb];
                    cohAddF(dst + (bb << 9) + tid, acch);
                }
                __syncthreads();  // drain adds before count
                if (tid == 0) cohAddInt(hpCnt + t + 1, 1);
            }
            __syncthreads();
        }
    } else if (bx < 96) {
        // ================= SC =================
        const int id = bx - 32;
        const int b = id >> 3, lq = id & 7;
        float* hpS = shm;          // 512
        float* vS  = shm + 512;    // 512
        vS[tid] = attnV[tid];
        __syncthreads();
        const int kq = tid & 63, lg = tid >> 6;
        for (int t = 0; t < T_; ++t) {
            const int par = t & 1;
            const float tagi = (float)(t + 1);
            // ---- detect hpCnt[t]==32 (monotone) then one-RT reduced read ----
            for (;;) {
                if (cohLoadInt(hpCnt + t) == 32) break;
                __builtin_amdgcn_s_sleep(2);
            }
            hpS[tid] = cohLoadF(hpSum + (size_t)t * 4096 + (b << 9) + tid);
            __syncthreads();
            u64* dst = scEx + par * 2048 + (b << 8);
#pragma unroll
            for (int i = 0; i < 4; ++i) {
                int ll = lg + (i << 3);
                const float* ep = encProj + (((size_t)(b << 8) + (lq << 5) + ll) << 9);
                float sc = 0.f;
#pragma unroll
                for (int m = 0; m < 8; ++m) {
                    int k = kq + (m << 6);
                    sc += vS[k] * ftanh(ep[k] + hpS[k]);
                }
#pragma unroll
                for (int off = 32; off; off >>= 1) sc += __shfl_xor(sc, off);
                if (kq == 0) cohStoreU64(dst + (lq << 5) + ll, packF2(sc, tagi));
            }
            __syncthreads();
        }
    } else if (bx < 160) {
        // ================= WT =================
        const int id = bx - 96;
        const int b = id >> 3, cq = id & 7;
        const int c = tid & 63, lg = tid >> 6;
        float* aS = shm;          // 256
        float* rS = shm + 256;    // 16
        float* wS = shm + 288;    // 512
        float* lp = shm + 800;    // 64
        for (int t = 0; t < T_; ++t) {
            const int par = t & 1;
            const float tagi = (float)(t + 1);
            float sc = 0.f;
            if (tid < 256) {
                const u64* src = scEx + par * 2048 + (b << 8) + tid;
                for (;;) {
                    float2 f = asF2(cohLoadU64(src));
                    if (f.y == tagi) { sc = f.x; break; }
                    __builtin_amdgcn_s_sleep(1);
                }
            }
            // shfl softmax (waves 0-3 hold the 256 scores)
            float m = (tid < 256) ? sc : -1e30f;
#pragma unroll
            for (int off = 32; off; off >>= 1) m = fmaxf(m, __shfl_xor(m, off));
            if ((tid & 63) == 0) rS[tid >> 6] = m;
            __syncthreads();
            float mx = fmaxf(fmaxf(rS[0], rS[1]), fmaxf(rS[2], rS[3]));
            float e = (tid < 256) ? __expf(sc - mx) : 0.f;
            float ssum = e;
#pragma unroll
            for (int off = 32; off; off >>= 1) ssum += __shfl_xor(ssum, off);
            if ((tid & 63) == 0) rS[8 + (tid >> 6)] = ssum;
            if (tid < 256) aS[tid] = e;
            __syncthreads();
            float inv = 1.f / (rS[8] + rS[9] + rS[10] + rS[11]);
            // weighted cols (complete, no cross-WG reduce); encOut slice L2-hot
            float acc = 0.f;
#pragma unroll
            for (int mm = 0; mm < 32; ++mm) {
                int l = lg + (mm << 3);
                acc += aS[l] * encOut[(((size_t)(b << 8) + l) << 9) + (cq << 6) + c];
            }
            wS[lg * 64 + c] = acc;
            __syncthreads();
            if (tid < 64) {
                float wv = 0.f;
#pragma unroll
                for (int q = 0; q < 8; ++q) wv += wS[q * 64 + tid];
                wv *= inv;
                cohStoreU64(wtEx + par * 4096 + (b << 9) + (cq << 6) + tid, packF2(wv, tagi));
                lp[tid] = wv * wEff[512 + (cq << 6) + tid];
            }
            __syncthreads();
            if (tid == 0) {
                float pc = 0.f;
                for (int q = 0; q < 64; ++q) pc += lp[q];
                cpart[(b * T_ + t) * 48 + 32 + cq] = pc;
            }
            __syncthreads();
        }
    } else if (bx < 164) {
        // ================= encdot (shadow) =================
        int wid = tid >> 6, lane = tid & 63;
        int gw = (bx - 160) * 8 + wid;  // 32 waves
        for (int o = gw; o < 2048; o += 32) {
            const float* row = encOut + ((size_t)o << 9);
            float s = 0.f;
            for (int k = lane; k < 512; k += 64) s += row[k] * wEff[k];
            for (int off = 32; off; off >>= 1) s += __shfl_down(s, off);
            if (lane == 0) encDot[o] = s;
        }
    } else {
        // ================= edot4 (shadow) =================
        int wg = bx - 164;              // 24 WGs x 8 rows
        int o = wg * 8 + (tid >> 6);
        int lane = tid & 63;
        const float* row = emb + (size_t)idxTok[o] * E_;
        const float* w = wEff + 1536;
        float s = 0.f;
        for (int k = lane; k < 512; k += 64) s += row[k] * w[k];
        for (int off = 32; off; off >>= 1) s += __shfl_down(s, off);
        if (lane == 0) eDot4[o] = s;
    }
}

// c[b,t] = eDot4 + bEff + sum of 40 partials (32 GRU + 8 WT)
__global__ void k_csum(const float* __restrict__ cpart, const float* __restrict__ eDot4,
                       const float* __restrict__ bEff, float* __restrict__ cBuf) {
    int tid = threadIdx.x;
    if (tid < 192) {
        int b = tid / 24, t = tid % 24;
        float acc = eDot4[t * 8 + b] + bEff[0];
        const float* p = cpart + (b * T_ + t) * 48;
#pragma unroll
        for (int k = 0; k < 40; ++k) acc += p[k];
        cBuf[b * T_ + t] = acc;
    }
}

// out[b,t,l-part] = enc_dot[b,l] + c[b,t]
__global__ void k_final(const float* __restrict__ encDot, const float* __restrict__ c,
                        float* __restrict__ out) {
    int idx = blockIdx.x * 256 + threadIdx.x;  // grid 192 -> 49152
    const int half = B_ * T_ * S_;
    int w = idx < half ? idx : idx - half;
    int b = w / (T_ * S_);
    int r = w % (T_ * S_);
    int t = r / S_, sidx = r % S_;
    int l = (idx < half) ? sidx : (S_ + sidx);
    out[idx] = encDot[b * L_ + l] + c[b * T_ + t];
}

// ---------------------------------------------------------------------------
extern "C" void kernel_launch(void* const* d_in, const int* in_sizes, int n_in,
                              void* d_out, int out_size, void* d_ws, size_t ws_size,
                              hipStream_t stream) {
    const int* pre = (const int*)d_in[0];
    const int* post = (const int*)d_in[1];
    const int* trg = (const int*)d_in[2];
    const float* emb = (const float*)d_in[3];
    const float* WihPre = (const float*)d_in[4];
    const float* WhhPre = (const float*)d_in[5];
    const float* bihPre = (const float*)d_in[6];
    const float* bhhPre = (const float*)d_in[7];
    const float* WihPost = (const float*)d_in[8];
    const float* WhhPost = (const float*)d_in[9];
    const float* bihPost = (const float*)d_in[10];
    const float* bhhPost = (const float*)d_in[11];
    const float* fcEncW = (const float*)d_in[12];
    const float* fcEncB = (const float*)d_in[13];
    const float* attnW = (const float*)d_in[14];
    const float* attnB = (const float*)d_in[15];
    const float* attnV = (const float*)d_in[16];
    const float* WihDec = (const float*)d_in[17];
    const float* WhhDec = (const float*)d_in[18];
    const float* bihDec = (const float*)d_in[19];
    const float* bhhDec = (const float*)d_in[20];
    const float* fcHidW = (const float*)d_in[21];
    const float* fcHidB = (const float*)d_in[22];
    const float* fcOutW = (const float*)d_in[23];
    const float* fcOutB = (const float*)d_in[24];
    float* outp = (float*)d_out;

    float* base = (float*)d_ws;
    size_t off = 0;
    auto alloc = [&](size_t n) {
        float* p = base + off;
        off += (n + 63) & ~(size_t)63;
        return p;
    };
    float* giE = alloc(192 * 1536);
    float* encOut = alloc(8 * 256 * 512);
    float* encProj = alloc(8 * 256 * 512);
    float* wEff = alloc(2048);
    float* bEff = alloc(64);
    float* encDot = alloc(2048);
    float* eDot4 = alloc(256);
    float* hBuf = alloc(4096);
    float* cBuf = alloc(256);
    // contiguous cleared exchange region:
    float* encExF = alloc(32768);     // 2 x 16 x 512 u64   encoder h
    float* hExF   = alloc(16384);     // 2 x 4096 u64       decoder h
    float* scExF  = alloc(8192);      // 2 x 2048 u64       scores
    float* wtExF  = alloc(16384);     // 2 x 4096 u64       weighted
    float* hpSumF = alloc(98304);     // 24 x 4096 f32      hp push-reduce
    float* hpCntF = alloc(64);        // hpCnt[24] ints
    float* cpart = alloc(8 * 24 * 48);
    int* idxPre = (int*)alloc(1024);
    int* idxPost = (int*)alloc(1024);
    int* idxTok = (int*)alloc(256);

    const int clearN = (32768 + 16384 + 8192 + 16384 + 98304 + 64) / 2;  // u64 slots
    k_boot<<<128, 256, 0, stream>>>(pre, post, trg, idxPre, idxPost, idxTok, wEff,
                                    (u64*)encExF, clearN);
    k_encoder<<<256, 512, 0, stream>>>(emb, idxPre, idxPost, WihPre, WihPost,
                                       bihPre, bihPost, WhhPre, WhhPost,
                                       bhhPre, bhhPost, encOut, (u64*)encExF);
    k_mid<<<473, 256, 0, stream>>>(emb, idxTok, WihDec, bihDec, giE,
                                   encOut, attnW, attnB, encProj,
                                   fcHidW, fcHidB, fcOutW, fcOutB, wEff, bEff,
                                   fcEncW, fcEncB, hBuf);
    k_decoder<<<188, 512, 0, stream>>>(encOut, encProj, attnW, attnV,
                                       WihDec, WhhDec, bhhDec, giE, wEff, hBuf,
                                       emb, idxTok,
                                       (u64*)hExF, hpSumF, (int*)hpCntF,
                                       (u64*)scExF, (u64*)wtExF,
                                       cpart, encDot, eDot4);
    k_csum<<<1, 256, 0, stream>>>(cpart, eDot4, bEff, cBuf);
    k_final<<<192, 256, 0, stream>>>(encDot, cBuf, outp);
}